// Round 5
// baseline (220.354 us; speedup 1.0000x reference)
//
#include <hip/hip_runtime.h>
#include <stdint.h>

typedef __attribute__((ext_vector_type(4))) float f32x4;
typedef __attribute__((ext_vector_type(8))) short short8;
typedef __attribute__((ext_vector_type(4))) unsigned int u32x4;

__device__ __forceinline__ unsigned short f2bf(float x) {
  union { float f; unsigned int u; } v; v.f = x;
  unsigned int r = (v.u + 0x7fffu + ((v.u >> 16) & 1u)) >> 16;  // RNE truncate
  return (unsigned short)r;
}

__device__ __forceinline__ f32x4 ld4(const float* p) { return *(const f32x4*)p; }

// out[b] = (adj[b] with zero diagonal) @ means[b]
// adj: [32][1024][1024] f32, means: [32][1024][128] f32, out: [32][1024][128] f32
// Grid: 256 WGs (32 batches x 8 row-tiles of 128), 512 threads = 8 waves.
// Wave w owns rows [rbase + 16w, +16): A (adj) loaded global->reg, converted to
// bf16 in-reg (diagonal zeroed during convert). B (means) double-buffered in
// LDS in fragment-major layout: frag(n,s) lane l reads 16B at (n*2+s)*1024+l*16.
__global__ __launch_bounds__(512) void gcn_kernel(
    const float* __restrict__ means, const float* __restrict__ adj,
    float* __restrict__ out) {
  __shared__ char ldsB[32768];  // 2 x 16 KiB (64x128 bf16 tile)

  const int tid = (int)threadIdx.x;
  const int l = tid & 63;
  const int w = tid >> 6;
  const int bid = (int)blockIdx.x;
  // XCD swizzle: the 8 row-tiles of one batch share bid%8 (same XCD L2)
  const int batch = (bid & 7) * 4 + (bid >> 6);
  const int rtile = (bid >> 3) & 7;
  const int rbase = rtile * 128;

  const float* aB = adj + (size_t)batch * 1048576;
  const float* mB = means + (size_t)batch * 131072;
  float* oB = out + (size_t)batch * 131072;

  // A-fragment addressing: lane l holds A row (l&15), k = 8*(l>>4)+e
  const int arow = rbase + w * 16 + (l & 15);  // within-batch row 0..1023
  const int kg = (l >> 4) * 8;
  const float* aP = aB + (size_t)arow * 1024 + kg;

  // B staging: thread t decodes (n=t>>6, s=(t>>5)&1, g=(t>>3)&3, fc=2*(t&7)),
  // loads 8 k-consecutive floats for columns fc and fc+1 of n-block n,
  // writes 32 contiguous LDS bytes at t*32 -> fragment-major layout.
  const int n_t = tid >> 6;
  const int s_t = (tid >> 5) & 1;
  const int g_t = (tid >> 3) & 3;
  const int fc_t = (tid & 7) * 2;
  const float* bP = mB + (size_t)(s_t * 32 + g_t * 8) * 128 + n_t * 16 + fc_t;

  char* wP = ldsB + tid * 32;        // staging write base (buf 0)
  const char* rP = ldsB + l * 16;    // fragment read base (buf 0)

  f32x4 acc[8];
#pragma unroll
  for (int n = 0; n < 8; ++n) { f32x4 z = {0.f, 0.f, 0.f, 0.f}; acc[n] = z; }

  f32x4 A0[4], A1[4];
  float Ba0[8], Bb0[8], Ba1[8], Bb1[8];

  auto loadA = [&](int kt, f32x4 A[4]) {
    const float* p = aP + kt * 64;
    A[0] = ld4(p); A[1] = ld4(p + 4); A[2] = ld4(p + 32); A[3] = ld4(p + 36);
  };
  auto loadB = [&](int kt, float Ba[8], float Bb[8]) {
    const float* p = bP + kt * 8192;
#pragma unroll
    for (int e = 0; e < 8; ++e) { Ba[e] = p[e * 128]; Bb[e] = p[e * 128 + 1]; }
  };
  auto stageB = [&](int buf, const float Ba[8], const float Bb[8]) {
    union { u32x4 q; unsigned short h[8]; } u0, u1;
#pragma unroll
    for (int e = 0; e < 8; ++e) { u0.h[e] = f2bf(Ba[e]); u1.h[e] = f2bf(Bb[e]); }
    char* p = wP + buf * 16384;
    *(u32x4*)p = u0.q;
    *(u32x4*)(p + 16) = u1.q;
  };
  auto compute = [&](int buf, int kt, const f32x4 A[4]) {
    short8 af0, af1;
    {
      union { short8 s; unsigned short h[8]; } u0, u1;
      const int jb = kt * 64 + kg;  // global k of A[0][0]
#pragma unroll
      for (int e = 0; e < 4; ++e) {
        u0.h[e]     = f2bf((jb + e      == arow) ? 0.f : A[0][e]);
        u0.h[e + 4] = f2bf((jb + 4 + e  == arow) ? 0.f : A[1][e]);
        u1.h[e]     = f2bf((jb + 32 + e == arow) ? 0.f : A[2][e]);
        u1.h[e + 4] = f2bf((jb + 36 + e == arow) ? 0.f : A[3][e]);
      }
      af0 = u0.s; af1 = u1.s;
    }
    const char* base = rP + buf * 16384;
#pragma unroll
    for (int n = 0; n < 8; ++n) {
      short8 bf0 = *(const short8*)(base + (n * 2 + 0) * 1024);
      acc[n] = __builtin_amdgcn_mfma_f32_16x16x32_bf16(af0, bf0, acc[n], 0, 0, 0);
      short8 bf1 = *(const short8*)(base + (n * 2 + 1) * 1024);
      acc[n] = __builtin_amdgcn_mfma_f32_16x16x32_bf16(af1, bf1, acc[n], 0, 0, 0);
    }
  };

  // Prologue: stage tile 0
  loadA(0, A0);
  loadB(0, Ba0, Bb0);
  stageB(0, Ba0, Bb0);
  __syncthreads();

  // Main loop: 16 K-steps, unrolled x2 for double buffer + register rotation
  for (int kt = 0; kt < 16; kt += 2) {
    // even step: compute buf0 (tile kt), stage tile kt+1 -> buf1
    loadA(kt + 1, A1);
    loadB(kt + 1, Ba1, Bb1);
    compute(0, kt, A0);
    stageB(1, Ba1, Bb1);
    __syncthreads();

    // odd step: compute buf1 (tile kt+1), stage tile kt+2 -> buf0
    if (kt + 2 < 16) {
      loadA(kt + 2, A0);
      loadB(kt + 2, Ba0, Bb0);
    }
    compute(1, kt + 1, A1);
    if (kt + 2 < 16) stageB(0, Ba0, Bb0);
    __syncthreads();
  }

  // Epilogue: C/D layout col = l&15, row = (l>>4)*4 + j
  const int orow = rbase + w * 16 + (l >> 4) * 4;
  const int ocol = l & 15;
  float* op = oB + (size_t)orow * 128 + ocol;
#pragma unroll
  for (int n = 0; n < 8; ++n)
#pragma unroll
    for (int j = 0; j < 4; ++j)
      op[j * 128 + n * 16] = acc[n][j];
}

extern "C" void kernel_launch(void* const* d_in, const int* in_sizes, int n_in,
                              void* d_out, int out_size, void* d_ws, size_t ws_size,
                              hipStream_t stream) {
  const float* means = (const float*)d_in[0];  // regional_means (32,1024,128)
  const float* adj = (const float*)d_in[1];    // adj (32,1024,1024)
  float* out = (float*)d_out;                  // (32,1024,128) f32
  hipLaunchKernelGGL(gcn_kernel, dim3(256), dim3(512), 0, stream, means, adj, out);
}

// Round 6
// 216.843 us; speedup vs baseline: 1.0162x; 1.0162x over previous
//
#include <hip/hip_runtime.h>
#include <hip/hip_bf16.h>
#include <stdint.h>

typedef __attribute__((ext_vector_type(4))) float f32x4;
typedef __attribute__((ext_vector_type(2))) float f32x2;
typedef __attribute__((ext_vector_type(8))) short short8;
typedef __attribute__((ext_vector_type(4))) unsigned int u32x4;

__device__ __forceinline__ unsigned short f2bf(float x) {
  __hip_bfloat16 h = __float2bfloat16(x);  // RNE; compiler fuses pairs to v_cvt_pk_bf16_f32
  union { __hip_bfloat16 b; unsigned short s; } u; u.b = h;
  return u.s;
}
__device__ __forceinline__ unsigned int pkbf(float lo, float hi) {
  return (unsigned int)f2bf(lo) | ((unsigned int)f2bf(hi) << 16);
}
__device__ __forceinline__ f32x4 ld4(const float* p) { return *(const f32x4*)p; }

// out[b] = (adj[b] with zero diagonal) @ means[b]
// adj: [32][1024][1024] f32, means: [32][1024][128] f32, out: [32][1024][128] f32
// Grid: 256 WGs (32 batches x 8 row-tiles of 128), 512 threads = 8 waves.
// NOTE: no lambdas / no array function params — everything straight-line macros
// with named vector variables so SROA keeps all state in VGPRs (220us round-5
// result attributed to scratch spill through lambda array params).

#define MSK(v, k) (((k) == arow) ? 0.f : (v))

#define LOADA(kt, Aa, Ab, Ac, Ad) do {                                  \
    const float* p_ = aP + (kt) * 64;                                   \
    Aa = ld4(p_); Ab = ld4(p_ + 4); Ac = ld4(p_ + 32); Ad = ld4(p_ + 36); \
  } while (0)

#define LOADB(kt, B_) do {                                              \
    const f32x2* p_ = (const f32x2*)(bP + (size_t)(kt) * 8192);         \
    _Pragma("unroll") for (int e_ = 0; e_ < 8; ++e_) B_[e_] = p_[e_ * 64]; \
  } while (0)

#define STAGEB(buf, B_) do {                                            \
    u32x4 ua_, ub_;                                                     \
    ua_[0] = pkbf(B_[0].x, B_[1].x); ua_[1] = pkbf(B_[2].x, B_[3].x);   \
    ua_[2] = pkbf(B_[4].x, B_[5].x); ua_[3] = pkbf(B_[6].x, B_[7].x);   \
    ub_[0] = pkbf(B_[0].y, B_[1].y); ub_[1] = pkbf(B_[2].y, B_[3].y);   \
    ub_[2] = pkbf(B_[4].y, B_[5].y); ub_[3] = pkbf(B_[6].y, B_[7].y);   \
    char* p_ = wP + (buf) * 16384;                                      \
    *(u32x4*)p_ = ua_; *(u32x4*)(p_ + 16) = ub_;                        \
  } while (0)

#define COMPUTE(buf, kt, Aa, Ab, Ac, Ad) do {                           \
    short8 af0_, af1_;                                                  \
    {                                                                   \
      union { u32x4 q; short8 s; } u0_, u1_;                            \
      if ((kt) == diag_kt) { /* wave-uniform: diag falls in this k-tile */ \
        const int jb_ = (kt) * 64 + kg;                                 \
        u0_.q[0] = pkbf(MSK(Aa[0], jb_ + 0),  MSK(Aa[1], jb_ + 1));     \
        u0_.q[1] = pkbf(MSK(Aa[2], jb_ + 2),  MSK(Aa[3], jb_ + 3));     \
        u0_.q[2] = pkbf(MSK(Ab[0], jb_ + 4),  MSK(Ab[1], jb_ + 5));     \
        u0_.q[3] = pkbf(MSK(Ab[2], jb_ + 6),  MSK(Ab[3], jb_ + 7));     \
        u1_.q[0] = pkbf(MSK(Ac[0], jb_ + 32), MSK(Ac[1], jb_ + 33));    \
        u1_.q[1] = pkbf(MSK(Ac[2], jb_ + 34), MSK(Ac[3], jb_ + 35));    \
        u1_.q[2] = pkbf(MSK(Ad[0], jb_ + 36), MSK(Ad[1], jb_ + 37));    \
        u1_.q[3] = pkbf(MSK(Ad[2], jb_ + 38), MSK(Ad[3], jb_ + 39));    \
      } else {                                                          \
        u0_.q[0] = pkbf(Aa[0], Aa[1]); u0_.q[1] = pkbf(Aa[2], Aa[3]);   \
        u0_.q[2] = pkbf(Ab[0], Ab[1]); u0_.q[3] = pkbf(Ab[2], Ab[3]);   \
        u1_.q[0] = pkbf(Ac[0], Ac[1]); u1_.q[1] = pkbf(Ac[2], Ac[3]);   \
        u1_.q[2] = pkbf(Ad[0], Ad[1]); u1_.q[3] = pkbf(Ad[2], Ad[3]);   \
      }                                                                 \
      af0_ = u0_.s; af1_ = u1_.s;                                       \
    }                                                                   \
    const char* base_ = rP + (buf) * 16384;                             \
    _Pragma("unroll")                                                   \
    for (int n_ = 0; n_ < 8; ++n_) {                                    \
      short8 bf0_ = *(const short8*)(base_ + (n_ * 2 + 0) * 1024);      \
      acc[n_] = __builtin_amdgcn_mfma_f32_16x16x32_bf16(af0_, bf0_, acc[n_], 0, 0, 0); \
      short8 bf1_ = *(const short8*)(base_ + (n_ * 2 + 1) * 1024);      \
      acc[n_] = __builtin_amdgcn_mfma_f32_16x16x32_bf16(af1_, bf1_, acc[n_], 0, 0, 0); \
    }                                                                   \
  } while (0)

__global__ __launch_bounds__(512) void gcn_kernel(
    const float* __restrict__ means, const float* __restrict__ adj,
    float* __restrict__ out) {
  __shared__ char ldsB[32768];  // 2 x 16 KiB (64x128 bf16 tile, fragment-major)

  const int tid = (int)threadIdx.x;
  const int l = tid & 63;
  const int w = tid >> 6;
  const int bid = (int)blockIdx.x;
  // XCD swizzle: the 8 row-tiles of one batch share bid%8 (same XCD L2);
  // each XCD sees 4 batches -> 4 x 512KB means panels, L2-resident.
  const int batch = (bid & 7) * 4 + (bid >> 6);
  const int rtile = (bid >> 3) & 7;
  const int rbase = rtile * 128;

  const float* aB = adj + (size_t)batch * 1048576;
  const float* mB = means + (size_t)batch * 131072;
  float* oB = out + (size_t)batch * 131072;

  // A-fragment: lane l holds A row (l&15), k = 8*(l>>4)+e
  const int arow = rbase + w * 16 + (l & 15);  // within-batch row
  const int kg = (l >> 4) * 8;
  const float* aP = aB + (size_t)arow * 1024 + kg;
  const int diag_kt = arow >> 6;  // wave-uniform (16 rows per wave, 64-aligned block)

  // B staging: thread t -> (n=t>>6, s=(t>>5)&1, g=(t>>3)&3, fc=2*(t&7));
  // loads 8 k-consecutive float2 (cols fc,fc+1), writes 32B at t*32 ->
  // fragment-major LDS: frag(n,s) lane l reads 16B at (n*2+s)*1024 + l*16.
  const int n_t = tid >> 6;
  const int s_t = (tid >> 5) & 1;
  const int g_t = (tid >> 3) & 3;
  const int fc_t = (tid & 7) * 2;
  const float* bP = mB + (size_t)(s_t * 32 + g_t * 8) * 128 + n_t * 16 + fc_t;

  char* wP = ldsB + tid * 32;        // staging write base (buf 0)
  const char* rP = ldsB + l * 16;    // fragment read base (buf 0)

  f32x4 acc[8];  // constant-indexed in unrolled loops only -> stays in VGPRs
#pragma unroll
  for (int n = 0; n < 8; ++n) { f32x4 z = {0.f, 0.f, 0.f, 0.f}; acc[n] = z; }

  f32x4 A00, A01, A02, A03, A10, A11, A12, A13;
  f32x2 B0v[8], B1v[8];  // constant-indexed only

  // Prologue: stage tile 0
  LOADA(0, A00, A01, A02, A03);
  LOADB(0, B0v);
  STAGEB(0, B0v);
  __syncthreads();

  for (int kt = 0; kt < 16; kt += 2) {
    // even: compute buf0 (tile kt), prefetch+stage tile kt+1 -> buf1
    LOADA(kt + 1, A10, A11, A12, A13);
    LOADB(kt + 1, B1v);
    COMPUTE(0, kt, A00, A01, A02, A03);
    STAGEB(1, B1v);
    __syncthreads();

    // odd: compute buf1 (tile kt+1), prefetch+stage tile kt+2 -> buf0
    if (kt + 2 < 16) {
      LOADA(kt + 2, A00, A01, A02, A03);
      LOADB(kt + 2, B0v);
    }
    COMPUTE(1, kt + 1, A10, A11, A12, A13);
    if (kt + 2 < 16) STAGEB(0, B0v);
    __syncthreads();
  }

  // Epilogue: C/D layout col = l&15, row = (l>>4)*4 + j
  const int orow = rbase + w * 16 + (l >> 4) * 4;
  const int ocol = l & 15;
  float* op = oB + (size_t)orow * 128 + ocol;
#pragma unroll
  for (int n = 0; n < 8; ++n)
#pragma unroll
    for (int j = 0; j < 4; ++j)
      op[j * 128 + n * 16] = acc[n][j];
}

extern "C" void kernel_launch(void* const* d_in, const int* in_sizes, int n_in,
                              void* d_out, int out_size, void* d_ws, size_t ws_size,
                              hipStream_t stream) {
  const float* means = (const float*)d_in[0];  // regional_means (32,1024,128)
  const float* adj = (const float*)d_in[1];    // adj (32,1024,1024)
  float* out = (float*)d_out;                  // (32,1024,128) f32
  hipLaunchKernelGGL(gcn_kernel, dim3(256), dim3(512), 0, stream, means, adj, out);
}

// Round 7
// 213.594 us; speedup vs baseline: 1.0316x; 1.0152x over previous
//
#include <hip/hip_runtime.h>
#include <hip/hip_bf16.h>
#include <stdint.h>

typedef __attribute__((ext_vector_type(4))) float f32x4;
typedef __attribute__((ext_vector_type(2))) float f32x2;
typedef __attribute__((ext_vector_type(8))) short short8;
typedef __attribute__((ext_vector_type(4))) unsigned int u32x4;

__device__ __forceinline__ unsigned short f2bf(float x) {
  __hip_bfloat16 h = __float2bfloat16(x);  // RNE; pairs fuse to v_cvt_pk_bf16_f32
  union { __hip_bfloat16 b; unsigned short s; } u; u.b = h;
  return u.s;
}
__device__ __forceinline__ unsigned int pkbf(float lo, float hi) {
  return (unsigned int)f2bf(lo) | ((unsigned int)f2bf(hi) << 16);
}
__device__ __forceinline__ f32x4 ld4(const float* p) { return *(const f32x4*)p; }

// out[b] = (adj[b] with zero diagonal) @ means[b]
// adj: [32][1024][1024] f32, means: [32][1024][128] f32, out: [32][1024][128] f32
// Grid: 256 WGs (32 batches x 8 row-tiles of 128), 512 threads = 8 waves.
//
// R7 change: PHASE-STAGGERED K-LOOP. All WGs previously streamed k-tile kt in
// lockstep; since adj rows are 4KB-strided, the whole chip's reads had addr
// bits [8:11] frozen (= kt*256 mod 4K) -> HBM channel/bank concentration,
// ~0.77 TB/s effective. WG bid now starts at kt0=(bid>>3)&15 and iterates
// k=(kt0+i)%16 (sum over k is order-independent); co-resident WGs cover all
// 16 phases -> channel-uniform traffic.

#define MSK(v, k) (((k) == arow) ? 0.f : (v))

#define LOADA(kt, Aa, Ab, Ac, Ad) do {                                  \
    const float* p_ = aP + (kt) * 64;                                   \
    Aa = ld4(p_); Ab = ld4(p_ + 4); Ac = ld4(p_ + 32); Ad = ld4(p_ + 36); \
  } while (0)

#define LOADB(kt, B_) do {                                              \
    const f32x2* p_ = (const f32x2*)(bP + (size_t)(kt) * 8192);         \
    _Pragma("unroll") for (int e_ = 0; e_ < 8; ++e_) B_[e_] = p_[e_ * 64]; \
  } while (0)

#define STAGEB(buf, B_) do {                                            \
    u32x4 ua_, ub_;                                                     \
    ua_[0] = pkbf(B_[0].x, B_[1].x); ua_[1] = pkbf(B_[2].x, B_[3].x);   \
    ua_[2] = pkbf(B_[4].x, B_[5].x); ua_[3] = pkbf(B_[6].x, B_[7].x);   \
    ub_[0] = pkbf(B_[0].y, B_[1].y); ub_[1] = pkbf(B_[2].y, B_[3].y);   \
    ub_[2] = pkbf(B_[4].y, B_[5].y); ub_[3] = pkbf(B_[6].y, B_[7].y);   \
    char* p_ = wP + (buf) * 16384;                                      \
    *(u32x4*)p_ = ua_; *(u32x4*)(p_ + 16) = ub_;                        \
  } while (0)

#define COMPUTE(buf, kt, Aa, Ab, Ac, Ad) do {                           \
    short8 af0_, af1_;                                                  \
    {                                                                   \
      union { u32x4 q; short8 s; } u0_, u1_;                            \
      if ((kt) == diag_kt) { /* wave-uniform: diag falls in this k-tile */ \
        const int jb_ = (kt) * 64 + kg;                                 \
        u0_.q[0] = pkbf(MSK(Aa[0], jb_ + 0),  MSK(Aa[1], jb_ + 1));     \
        u0_.q[1] = pkbf(MSK(Aa[2], jb_ + 2),  MSK(Aa[3], jb_ + 3));     \
        u0_.q[2] = pkbf(MSK(Ab[0], jb_ + 4),  MSK(Ab[1], jb_ + 5));     \
        u0_.q[3] = pkbf(MSK(Ab[2], jb_ + 6),  MSK(Ab[3], jb_ + 7));     \
        u1_.q[0] = pkbf(MSK(Ac[0], jb_ + 32), MSK(Ac[1], jb_ + 33));    \
        u1_.q[1] = pkbf(MSK(Ac[2], jb_ + 34), MSK(Ac[3], jb_ + 35));    \
        u1_.q[2] = pkbf(MSK(Ad[0], jb_ + 36), MSK(Ad[1], jb_ + 37));    \
        u1_.q[3] = pkbf(MSK(Ad[2], jb_ + 38), MSK(Ad[3], jb_ + 39));    \
      } else {                                                          \
        u0_.q[0] = pkbf(Aa[0], Aa[1]); u0_.q[1] = pkbf(Aa[2], Aa[3]);   \
        u0_.q[2] = pkbf(Ab[0], Ab[1]); u0_.q[3] = pkbf(Ab[2], Ab[3]);   \
        u1_.q[0] = pkbf(Ac[0], Ac[1]); u1_.q[1] = pkbf(Ac[2], Ac[3]);   \
        u1_.q[2] = pkbf(Ad[0], Ad[1]); u1_.q[3] = pkbf(Ad[2], Ad[3]);   \
      }                                                                 \
      af0_ = u0_.s; af1_ = u1_.s;                                       \
    }                                                                   \
    const char* base_ = rP + (buf) * 16384;                             \
    _Pragma("unroll")                                                   \
    for (int n_ = 0; n_ < 8; ++n_) {                                    \
      short8 bf0_ = *(const short8*)(base_ + (n_ * 2 + 0) * 1024);      \
      acc[n_] = __builtin_amdgcn_mfma_f32_16x16x32_bf16(af0_, bf0_, acc[n_], 0, 0, 0); \
      short8 bf1_ = *(const short8*)(base_ + (n_ * 2 + 1) * 1024);      \
      acc[n_] = __builtin_amdgcn_mfma_f32_16x16x32_bf16(af1_, bf1_, acc[n_], 0, 0, 0); \
    }                                                                   \
  } while (0)

__global__ __launch_bounds__(512) void gcn_kernel(
    const float* __restrict__ means, const float* __restrict__ adj,
    float* __restrict__ out) {
  __shared__ char ldsB[32768];  // 2 x 16 KiB (64x128 bf16 tile, fragment-major)

  const int tid = (int)threadIdx.x;
  const int l = tid & 63;
  const int w = tid >> 6;
  const int bid = (int)blockIdx.x;
  // XCD swizzle: the 8 row-tiles of one batch share bid%8 (same XCD L2);
  // each XCD sees 4 batches -> 4 x 512KB means panels, L2-resident.
  const int batch = (bid & 7) * 4 + (bid >> 6);
  const int rtile = (bid >> 3) & 7;
  const int rbase = rtile * 128;
  // K-phase stagger: co-resident WGs (same bid%8) get bid>>3 = 0..31 -> all
  // 16 phases covered uniformly per XCD.
  const int kt0 = (bid >> 3) & 15;

  const float* aB = adj + (size_t)batch * 1048576;
  const float* mB = means + (size_t)batch * 131072;
  float* oB = out + (size_t)batch * 131072;

  // A-fragment: lane l holds A row (l&15), k = 8*(l>>4)+e
  const int arow = rbase + w * 16 + (l & 15);  // within-batch row
  const int kg = (l >> 4) * 8;
  const float* aP = aB + (size_t)arow * 1024 + kg;
  const int diag_kt = arow >> 6;  // wave-uniform (16 rows per wave, 64-aligned)

  // B staging: thread t -> (n=t>>6, s=(t>>5)&1, g=(t>>3)&3, fc=2*(t&7));
  // loads 8 k-consecutive float2 (cols fc,fc+1), writes 32B at t*32 ->
  // fragment-major LDS: frag(n,s) lane l reads 16B at (n*2+s)*1024 + l*16.
  const int n_t = tid >> 6;
  const int s_t = (tid >> 5) & 1;
  const int g_t = (tid >> 3) & 3;
  const int fc_t = (tid & 7) * 2;
  const float* bP = mB + (size_t)(s_t * 32 + g_t * 8) * 128 + n_t * 16 + fc_t;

  char* wP = ldsB + tid * 32;        // staging write base (buf 0)
  const char* rP = ldsB + l * 16;    // fragment read base (buf 0)

  f32x4 acc[8];  // constant-indexed in unrolled loops only -> stays in VGPRs
#pragma unroll
  for (int n = 0; n < 8; ++n) { f32x4 z = {0.f, 0.f, 0.f, 0.f}; acc[n] = z; }

  f32x4 A00, A01, A02, A03, A10, A11, A12, A13;
  f32x2 B0v[8], B1v[8];  // constant-indexed only

  // Prologue: stage physical tile kt0
  LOADA(kt0, A00, A01, A02, A03);
  LOADB(kt0, B0v);
  STAGEB(0, B0v);
  __syncthreads();

  for (int i = 0; i < 16; i += 2) {
    const int k0 = (kt0 + i) & 15;
    const int k1 = (kt0 + i + 1) & 15;
    const int k2 = (kt0 + i + 2) & 15;

    // even: compute buf0 (tile k0), prefetch+stage tile k1 -> buf1
    LOADA(k1, A10, A11, A12, A13);
    LOADB(k1, B1v);
    COMPUTE(0, k0, A00, A01, A02, A03);
    STAGEB(1, B1v);
    __syncthreads();

    // odd: compute buf1 (tile k1), prefetch+stage tile k2 -> buf0
    if (i + 2 < 16) {
      LOADA(k2, A00, A01, A02, A03);
      LOADB(k2, B0v);
    }
    COMPUTE(1, k1, A10, A11, A12, A13);
    if (i + 2 < 16) STAGEB(0, B0v);
    __syncthreads();
  }

  // Epilogue: C/D layout col = l&15, row = (l>>4)*4 + j
  const int orow = rbase + w * 16 + (l >> 4) * 4;
  const int ocol = l & 15;
  float* op = oB + (size_t)orow * 128 + ocol;
#pragma unroll
  for (int n = 0; n < 8; ++n)
#pragma unroll
    for (int j = 0; j < 4; ++j)
      op[j * 128 + n * 16] = acc[n][j];
}

extern "C" void kernel_launch(void* const* d_in, const int* in_sizes, int n_in,
                              void* d_out, int out_size, void* d_ws, size_t ws_size,
                              hipStream_t stream) {
  const float* means = (const float*)d_in[0];  // regional_means (32,1024,128)
  const float* adj = (const float*)d_in[1];    // adj (32,1024,1024)
  float* out = (float*)d_out;                  // (32,1024,128) f32
  hipLaunchKernelGGL(gcn_kernel, dim3(256), dim3(512), 0, stream, means, adj, out);
}